// Round 1
// baseline (194.182 us; speedup 1.0000x reference)
//
#include <hip/hip_runtime.h>

// Fused Deep-Sets actor. bf16 MFMA (16x16x32), fp32 accum.
// prep kernel: ws16 = [W1T 256x64 | W2T 256x256 | RHOT 256x256 | HEADT 16x256] bf16
// main kernel: 1024 blocks x 256 thr, BM=64 rows/block, 4 waves x 64-col strips.

typedef __bf16 bf16x8 __attribute__((ext_vector_type(8)));
typedef float f32x4 __attribute__((ext_vector_type(4)));

#define LDH 264   // hbuf stride (elems), 528B: 16B-aligned, 2-way max bank alias
#define LDI 72    // inp stride, 144B
#define LDR 80    // raw f32 stride

__device__ __forceinline__ unsigned short f2bf(float f) {
  union { float f; unsigned u; } v; v.f = f;
  unsigned r = v.u + 0x7fffu + ((v.u >> 16) & 1u);  // RNE
  return (unsigned short)(r >> 16);
}

__device__ __forceinline__ f32x4 mfma16(bf16x8 a, bf16x8 b, f32x4 c) {
  return __builtin_amdgcn_mfma_f32_16x16x32_bf16(a, b, c, 0, 0, 0);
}

__global__ void actor_prep(const float* __restrict__ w1, const float* __restrict__ w2,
                           const float* __restrict__ rho, const float* __restrict__ mw,
                           const float* __restrict__ lw, unsigned short* __restrict__ ws16) {
  int idx = blockIdx.x * blockDim.x + threadIdx.x;
  const int T = 16384 + 65536 + 65536 + 4096;
  for (; idx < T; idx += gridDim.x * blockDim.x) {
    float v;
    if (idx < 16384) {                       // W1T[n][k], k padded 58->64
      int n = idx >> 6, k = idx & 63;
      v = (k < 58) ? w1[k * 256 + n] : 0.f;
    } else if (idx < 81920) {                // W2T[n][k]
      int o = idx - 16384; int n = o >> 8, k = o & 255;
      v = w2[k * 256 + n];
    } else if (idx < 147456) {               // RHOT[n][k]
      int o = idx - 81920; int n = o >> 8, k = o & 255;
      v = rho[k * 256 + n];
    } else {                                 // HEADT[n][k]: n<4 mean, 4..7 logstd, 8..15 zero
      int o = idx - 147456; int n = o >> 8, k = o & 255;
      v = (n < 4) ? mw[k * 4 + n] : ((n < 8) ? lw[k * 4 + (n - 4)] : 0.f);
    }
    ws16[idx] = f2bf(v);
  }
}

__global__ __launch_bounds__(256, 2) void actor_main(
    const float* __restrict__ obs, const float* __restrict__ ag, const float* __restrict__ g,
    const float* __restrict__ b1v, const float* __restrict__ b2v, const float* __restrict__ rbv,
    const float* __restrict__ mbv, const float* __restrict__ lbv,
    const unsigned short* __restrict__ w1t, const unsigned short* __restrict__ w2t,
    const unsigned short* __restrict__ rhot, const unsigned short* __restrict__ headt,
    float* __restrict__ out, int B) {
  __shared__ float raw[64 * LDR];            // 20480 B
  __shared__ unsigned short inp[64 * LDI];   //  9216 B
  __shared__ unsigned short hbuf[64 * LDH];  // 33792 B
  __shared__ int srcidx[64];                 //   256 B  (total 63744 < 64K)

  const int tid = threadIdx.x;
  const int lane = tid & 63;
  const int wv = tid >> 6;       // wave 0..3
  const int l15 = lane & 15;
  const int lq = lane >> 4;      // 0..3
  const int wbase = wv * 64;     // N-strip base
  const long brow = (long)blockIdx.x * 64;

  // ---- stage raw inputs (f32) ----
  for (int idx = tid; idx < 64 * 55; idx += 256) {
    int r = idx / 55, c = idx - r * 55;
    raw[r * LDR + c] = obs[(brow + r) * 55 + c];
  }
  for (int idx = tid; idx < 64 * 9; idx += 256) {
    int r = idx / 9, c = idx - r * 9;
    raw[r * LDR + 56 + c] = ag[(brow + r) * 9 + c];
    raw[r * LDR + 66 + c] = g[(brow + r) * 9 + c];
  }

  const f32x4 fzero = {0.f, 0.f, 0.f, 0.f};
  f32x4 pooled[4][4];
#pragma unroll
  for (int a = 0; a < 4; a++)
#pragma unroll
    for (int b = 0; b < 4; b++) pooled[a][b] = fzero;

  const int PI[6] = {0, 0, 1, 1, 2, 2};
  const int PJ[6] = {1, 2, 0, 2, 0, 1};

  for (int p = 0; p < 6; p++) {
    const int pi = PI[p], pj = PJ[p];
    __syncthreads();  // raw ready (p=0); hbuf/inp reads of prev iter done
    if (tid < 64) {   // col -> raw-index table for this perm (-1: 0.0, -2: 1.0)
      int c = tid, s;
      if (c < 3)       s = 56 + 3 * pi + c;
      else if (c < 6)  s = 56 + 3 * pj + (c - 3);
      else if (c < 9)  s = 66 + 3 * pi + (c - 6);
      else if (c < 12) s = 66 + 3 * pj + (c - 9);
      else if (c < 22) s = c - 12;
      else if (c < 25) s = ((c - 22) == pi) ? -2 : -1;
      else if (c < 40) s = 10 + 15 * pi + (c - 25);
      else if (c < 43) s = ((c - 40) == pj) ? -2 : -1;
      else if (c < 58) s = 10 + 15 * pj + (c - 43);
      else             s = -1;
      srcidx[c] = s;
    }
    __syncthreads();
    for (int idx = tid; idx < 64 * 64; idx += 256) {   // build 64x64 bf16 tile
      int r = idx >> 6, c = idx & 63;
      int s = srcidx[c];
      float v = (s >= 0) ? raw[r * LDR + s] : ((s == -2) ? 1.0f : 0.0f);
      inp[r * LDI + c] = f2bf(v);
    }
    __syncthreads();

    // ---- GEMM1: h = relu(inp @ W1 + b1), M=64 K=64, N-strip 64 ----
    f32x4 acc1[4][4];
#pragma unroll
    for (int a = 0; a < 4; a++)
#pragma unroll
      for (int b = 0; b < 4; b++) acc1[a][b] = fzero;
#pragma unroll
    for (int kk = 0; kk < 2; kk++) {
      bf16x8 af[4], bfr[4];
#pragma unroll
      for (int mt = 0; mt < 4; mt++)
        af[mt] = *(const bf16x8*)&inp[(mt * 16 + l15) * LDI + kk * 32 + lq * 8];
#pragma unroll
      for (int nt = 0; nt < 4; nt++)
        bfr[nt] = *(const bf16x8*)&w1t[(wbase + nt * 16 + l15) * 64 + kk * 32 + lq * 8];
#pragma unroll
      for (int mt = 0; mt < 4; mt++)
#pragma unroll
        for (int nt = 0; nt < 4; nt++)
          acc1[mt][nt] = mfma16(af[mt], bfr[nt], acc1[mt][nt]);
    }
#pragma unroll
    for (int nt = 0; nt < 4; nt++) {
      float bb = b1v[wbase + nt * 16 + l15];
#pragma unroll
      for (int mt = 0; mt < 4; mt++)
#pragma unroll
        for (int r = 0; r < 4; r++) {
          float hv = fmaxf(acc1[mt][nt][r] + bb, 0.f);
          hbuf[(mt * 16 + lq * 4 + r) * LDH + wbase + nt * 16 + l15] = f2bf(hv);
        }
    }
    __syncthreads();

    // ---- GEMM2: pooled += relu(h @ W2 + b2), K=256 ----
    f32x4 acc2[4][4];
#pragma unroll
    for (int a = 0; a < 4; a++)
#pragma unroll
      for (int b = 0; b < 4; b++) acc2[a][b] = fzero;
#pragma unroll
    for (int kk = 0; kk < 8; kk++) {
      bf16x8 af[4], bfr[4];
#pragma unroll
      for (int mt = 0; mt < 4; mt++)
        af[mt] = *(const bf16x8*)&hbuf[(mt * 16 + l15) * LDH + kk * 32 + lq * 8];
#pragma unroll
      for (int nt = 0; nt < 4; nt++)
        bfr[nt] = *(const bf16x8*)&w2t[(wbase + nt * 16 + l15) * 256 + kk * 32 + lq * 8];
#pragma unroll
      for (int mt = 0; mt < 4; mt++)
#pragma unroll
        for (int nt = 0; nt < 4; nt++)
          acc2[mt][nt] = mfma16(af[mt], bfr[nt], acc2[mt][nt]);
    }
#pragma unroll
    for (int nt = 0; nt < 4; nt++) {
      float bb = b2v[wbase + nt * 16 + l15];
#pragma unroll
      for (int mt = 0; mt < 4; mt++)
#pragma unroll
        for (int r = 0; r < 4; r++)
          pooled[mt][nt][r] += fmaxf(acc2[mt][nt][r] + bb, 0.f);
    }
  }

  __syncthreads();  // last GEMM2 hbuf reads done
  // ---- pooled -> hbuf (bf16) ----
#pragma unroll
  for (int nt = 0; nt < 4; nt++)
#pragma unroll
    for (int mt = 0; mt < 4; mt++)
#pragma unroll
      for (int r = 0; r < 4; r++)
        hbuf[(mt * 16 + lq * 4 + r) * LDH + wbase + nt * 16 + l15] = f2bf(pooled[mt][nt][r]);
  __syncthreads();

  // ---- GEMM3: x = relu(pooled @ rho_w1 + rho_b1) ----
  f32x4 acc3[4][4];
#pragma unroll
  for (int a = 0; a < 4; a++)
#pragma unroll
    for (int b = 0; b < 4; b++) acc3[a][b] = fzero;
#pragma unroll
  for (int kk = 0; kk < 8; kk++) {
    bf16x8 af[4], bfr[4];
#pragma unroll
    for (int mt = 0; mt < 4; mt++)
      af[mt] = *(const bf16x8*)&hbuf[(mt * 16 + l15) * LDH + kk * 32 + lq * 8];
#pragma unroll
    for (int nt = 0; nt < 4; nt++)
      bfr[nt] = *(const bf16x8*)&rhot[(wbase + nt * 16 + l15) * 256 + kk * 32 + lq * 8];
#pragma unroll
    for (int mt = 0; mt < 4; mt++)
#pragma unroll
      for (int nt = 0; nt < 4; nt++)
        acc3[mt][nt] = mfma16(af[mt], bfr[nt], acc3[mt][nt]);
  }
  __syncthreads();  // all hbuf reads done before overwrite
#pragma unroll
  for (int nt = 0; nt < 4; nt++) {
    float bb = rbv[wbase + nt * 16 + l15];
#pragma unroll
    for (int mt = 0; mt < 4; mt++)
#pragma unroll
      for (int r = 0; r < 4; r++) {
        float xv = fmaxf(acc3[mt][nt][r] + bb, 0.f);
        hbuf[(mt * 16 + lq * 4 + r) * LDH + wbase + nt * 16 + l15] = f2bf(xv);
      }
  }
  __syncthreads();

  // ---- GEMM4: heads. wave wv owns M-tile wv (16 rows), N=16 (mean|logstd|pad) ----
  f32x4 acc4 = fzero;
#pragma unroll
  for (int kk = 0; kk < 8; kk++) {
    bf16x8 a = *(const bf16x8*)&hbuf[(wv * 16 + l15) * LDH + kk * 32 + lq * 8];
    bf16x8 b = *(const bf16x8*)&headt[l15 * 256 + kk * 32 + lq * 8];
    acc4 = mfma16(a, b, acc4);
  }
  {
    int c = l15;
#pragma unroll
    for (int r = 0; r < 4; r++) {
      long gr = brow + wv * 16 + lq * 4 + r;
      float v = acc4[r];
      if (c < 4) {
        out[gr * 4 + c] = v + mbv[c];
      } else if (c < 8) {
        float u = fminf(fmaxf(v + lbv[c - 4], -20.f), 2.f);
        out[(long)B * 4 + gr * 4 + (c - 4)] = u;
      }
    }
  }
}

extern "C" void kernel_launch(void* const* d_in, const int* in_sizes, int n_in,
                              void* d_out, int out_size, void* d_ws, size_t ws_size,
                              hipStream_t stream) {
  const float* obs = (const float*)d_in[0];
  const float* ag  = (const float*)d_in[1];
  const float* g   = (const float*)d_in[2];
  const float* w1  = (const float*)d_in[3];
  const float* b1  = (const float*)d_in[4];
  const float* w2  = (const float*)d_in[5];
  const float* b2  = (const float*)d_in[6];
  const float* rw  = (const float*)d_in[7];
  const float* rb  = (const float*)d_in[8];
  const float* mw  = (const float*)d_in[9];
  const float* mb  = (const float*)d_in[10];
  const float* lw  = (const float*)d_in[11];
  const float* lb  = (const float*)d_in[12];
  int B = in_sizes[0] / 55;

  unsigned short* ws16 = (unsigned short*)d_ws;
  hipLaunchKernelGGL(actor_prep, dim3(256), dim3(256), 0, stream, w1, w2, rw, mw, lw, ws16);
  hipLaunchKernelGGL(actor_main, dim3(B / 64), dim3(256), 0, stream,
                     obs, ag, g, b1, b2, rb, mb, lb,
                     ws16, ws16 + 16384, ws16 + 81920, ws16 + 147456,
                     (float*)d_out, B);
}